// Round 2
// baseline (1052.507 us; speedup 1.0000x reference)
//
#include <hip/hip_runtime.h>

typedef float vf4 __attribute__((ext_vector_type(4)));
typedef float vf2 __attribute__((ext_vector_type(2)));

// Fetch the (x0, x0+1) horizontal texel pair from row y with zeros padding.
// Common case: one 8B load (pair fully inside). Rare edge cases predicated.
__device__ __forceinline__ vf2 fetch_pair(const float* __restrict__ tex, int N, int y, int x0) {
    vf2 r = {0.f, 0.f};
    if ((unsigned)y < (unsigned)N) {
        const float* row = tex + (size_t)(unsigned)y * (unsigned)N;
        if ((unsigned)x0 < (unsigned)(N - 1)) {
            __builtin_memcpy(&r, row + x0, sizeof(vf2));   // 4B-aligned 8B load
        } else if (x0 == -1) {
            r.y = row[0];
        } else if (x0 == N - 1) {
            r.x = row[N - 1];
        }
    }
    return r;
}

// One bilinear sample of an NxN texture at normalized coords (gx, gy) in [0,1].
// torch grid_sample(zeros, align_corners=False): ix = gx*N - 0.5
__device__ __forceinline__ float sample1(const float* __restrict__ tex, int N, float gx, float gy) {
    float ix = fmaf(gx, (float)N, -0.5f);
    float iy = fmaf(gy, (float)N, -0.5f);
    float x0f = floorf(ix);
    float y0f = floorf(iy);
    float wx = ix - x0f;
    float wy = iy - y0f;
    int x0 = (int)x0f;
    int y0 = (int)y0f;
    vf2 t = fetch_pair(tex, N, y0, x0);
    vf2 b = fetch_pair(tex, N, y0 + 1, x0);
    float top = fmaf(wx, t.y - t.x, t.x);
    float bot = fmaf(wx, b.y - b.x, b.x);
    return fmaf(wy, bot - top, top);
}

__device__ __forceinline__ float sample_all(const float* __restrict__ l1, const float* __restrict__ l2,
                                            const float* __restrict__ l3, const float* __restrict__ l4,
                                            float gx, float gy) {
    return sample1(l1, 2048, gx, gy) + sample1(l2, 1024, gx, gy)
         + sample1(l3,  512, gx, gy) + sample1(l4,  256, gx, gy);
}

__global__ void __launch_bounds__(256) tex_kernel(
    const vf4* __restrict__ xg,   // 2 float4 = 4 pixels' (x,y) pairs per thread
    const float* __restrict__ l1, const float* __restrict__ l2,
    const float* __restrict__ l3, const float* __restrict__ l4,
    vf4* __restrict__ out, int nquads) {
    int t = blockIdx.x * blockDim.x + threadIdx.x;
    if (t >= nquads) return;
    // 4 pixels per thread: 32B of coords in, 16B out, all coalesced + nontemporal
    vf4 a = __builtin_nontemporal_load(&xg[2 * t]);
    vf4 b = __builtin_nontemporal_load(&xg[2 * t + 1]);
    vf4 o;
    o.x = sample_all(l1, l2, l3, l4, a.x, a.y);
    o.y = sample_all(l1, l2, l3, l4, a.z, a.w);
    o.z = sample_all(l1, l2, l3, l4, b.x, b.y);
    o.w = sample_all(l1, l2, l3, l4, b.z, b.w);
    __builtin_nontemporal_store(o, &out[t]);
}

extern "C" void kernel_launch(void* const* d_in, const int* in_sizes, int n_in,
                              void* d_out, int out_size, void* d_ws, size_t ws_size,
                              hipStream_t stream) {
    const vf4* xg = (const vf4*)d_in[0];
    const float* l1 = (const float*)d_in[1];
    const float* l2 = (const float*)d_in[2];
    const float* l3 = (const float*)d_in[3];
    const float* l4 = (const float*)d_in[4];
    vf4* out = (vf4*)d_out;
    int nquads = out_size / 4;               // 4,194,304
    int blocks = (nquads + 255) / 256;       // 16,384
    tex_kernel<<<blocks, 256, 0, stream>>>(xg, l1, l2, l3, l4, out, nquads);
}

// Round 3
// 673.875 us; speedup vs baseline: 1.5619x; 1.5619x over previous
//
#include <hip/hip_runtime.h>

typedef float vf4 __attribute__((ext_vector_type(4)));
typedef float vf2 __attribute__((ext_vector_type(2)));
typedef _Float16 h4 __attribute__((ext_vector_type(4)));

// ---------- shared bilinear helpers (zeros padding, align_corners=False) ----------

// Fetch the (x0, x0+1) horizontal texel pair from row y with zeros padding.
__device__ __forceinline__ vf2 fetch_pair(const float* __restrict__ tex, int N, int y, int x0) {
    vf2 r = {0.f, 0.f};
    if ((unsigned)y < (unsigned)N) {
        const float* row = tex + (size_t)(unsigned)y * (unsigned)N;
        if ((unsigned)x0 < (unsigned)(N - 1)) {
            __builtin_memcpy(&r, row + x0, sizeof(vf2));   // 4B-aligned 8B load
        } else if (x0 == -1) {
            r.y = row[0];
        } else if (x0 == N - 1) {
            r.x = row[N - 1];
        }
    }
    return r;
}

// Bilinear sample at (already-scaled) texel-space coords ix, iy.
__device__ __forceinline__ float sample_ix(const float* __restrict__ tex, int N, float ix, float iy) {
    float x0f = floorf(ix);
    float y0f = floorf(iy);
    float wx = ix - x0f;
    float wy = iy - y0f;
    int x0 = (int)x0f;
    int y0 = (int)y0f;
    vf2 t = fetch_pair(tex, N, y0, x0);
    vf2 b = fetch_pair(tex, N, y0 + 1, x0);
    float top = fmaf(wx, t.y - t.x, t.x);
    float bot = fmaf(wx, b.y - b.x, b.x);
    return fmaf(wy, bot - top, top);
}

// Value of the 4-level sum F at fused-grid knot (fx, fy) = (jx, jy) in units of 1/4096.
// Level d has ix = gx*(2048/d) - 0.5 with gx = jx/4096  =>  ix = jx/(2d) - 0.5.
__device__ __forceinline__ float knotV(const float* __restrict__ l1, const float* __restrict__ l2,
                                       const float* __restrict__ l3, const float* __restrict__ l4,
                                       float fx, float fy) {
    float s;
    s  = sample_ix(l1, 2048, fmaf(fx, 0.5f,    -0.5f), fmaf(fy, 0.5f,    -0.5f));
    s += sample_ix(l2, 1024, fmaf(fx, 0.25f,   -0.5f), fmaf(fy, 0.25f,   -0.5f));
    s += sample_ix(l3,  512, fmaf(fx, 0.125f,  -0.5f), fmaf(fy, 0.125f,  -0.5f));
    s += sample_ix(l4,  256, fmaf(fx, 0.0625f, -0.5f), fmaf(fy, 0.0625f, -0.5f));
    return s;
}

// ---------- pass 1: build fused cell table R[4096][4096] (fp16x4 = 8B per cell) ----------
// R[jy][jx] = (V[jy][jx], V[jy][jx+1], V[jy+1][jx], V[jy+1][jx+1])
__global__ void __launch_bounds__(256) build_R(
    const float* __restrict__ l1, const float* __restrict__ l2,
    const float* __restrict__ l3, const float* __restrict__ l4,
    h4* __restrict__ R) {
    int t = blockIdx.x * 256 + threadIdx.x;     // 0 .. 2^24-1, == jy*4096 + jx
    float fx = (float)(t & 4095);
    float fy = (float)(t >> 12);
    float v00 = knotV(l1, l2, l3, l4, fx,        fy);
    float v01 = knotV(l1, l2, l3, l4, fx + 1.0f, fy);
    float v10 = knotV(l1, l2, l3, l4, fx,        fy + 1.0f);
    float v11 = knotV(l1, l2, l3, l4, fx + 1.0f, fy + 1.0f);
    h4 q = { (_Float16)v00, (_Float16)v01, (_Float16)v10, (_Float16)v11 };
    R[t] = q;                                    // coalesced 8B stores
}

// ---------- pass 2: one 8B gather + bilinear per pixel ----------
__device__ __forceinline__ float sample_R(const h4* __restrict__ R, float gx, float gy) {
    float u = gx * 4096.0f;
    float v = gy * 4096.0f;
    int jx = min((int)u, 4095);
    int jy = min((int)v, 4095);
    float wx = u - (float)jx;
    float wy = v - (float)jy;
    h4 q = R[((size_t)jy << 12) | (unsigned)jx]; // single aligned 8B gather
    float v00 = (float)q.x, v01 = (float)q.y, v10 = (float)q.z, v11 = (float)q.w;
    float top = fmaf(wx, v01 - v00, v00);
    float bot = fmaf(wx, v11 - v10, v10);
    return fmaf(wy, bot - top, top);
}

__global__ void __launch_bounds__(256) tex_kernel_fused(
    const vf4* __restrict__ xg, const h4* __restrict__ R,
    vf4* __restrict__ out, int nquads) {
    int t = blockIdx.x * blockDim.x + threadIdx.x;
    if (t >= nquads) return;
    vf4 a = __builtin_nontemporal_load(&xg[2 * t]);
    vf4 b = __builtin_nontemporal_load(&xg[2 * t + 1]);
    vf4 o;
    o.x = sample_R(R, a.x, a.y);
    o.y = sample_R(R, a.z, a.w);
    o.z = sample_R(R, b.x, b.y);
    o.w = sample_R(R, b.z, b.w);
    __builtin_nontemporal_store(o, &out[t]);
}

// ---------- fallback: direct 4-level sampling (round-2 kernel, known-good) ----------
__device__ __forceinline__ float sample1(const float* __restrict__ tex, int N, float gx, float gy) {
    return sample_ix(tex, N, fmaf(gx, (float)N, -0.5f), fmaf(gy, (float)N, -0.5f));
}

__global__ void __launch_bounds__(256) tex_kernel_direct(
    const vf4* __restrict__ xg,
    const float* __restrict__ l1, const float* __restrict__ l2,
    const float* __restrict__ l3, const float* __restrict__ l4,
    vf4* __restrict__ out, int nquads) {
    int t = blockIdx.x * blockDim.x + threadIdx.x;
    if (t >= nquads) return;
    vf4 a = __builtin_nontemporal_load(&xg[2 * t]);
    vf4 b = __builtin_nontemporal_load(&xg[2 * t + 1]);
    vf4 o;
    o.x = sample1(l1, 2048, a.x, a.y) + sample1(l2, 1024, a.x, a.y) + sample1(l3, 512, a.x, a.y) + sample1(l4, 256, a.x, a.y);
    o.y = sample1(l1, 2048, a.z, a.w) + sample1(l2, 1024, a.z, a.w) + sample1(l3, 512, a.z, a.w) + sample1(l4, 256, a.z, a.w);
    o.z = sample1(l1, 2048, b.x, b.y) + sample1(l2, 1024, b.x, b.y) + sample1(l3, 512, b.x, b.y) + sample1(l4, 256, b.x, b.y);
    o.w = sample1(l1, 2048, b.z, b.w) + sample1(l2, 1024, b.z, b.w) + sample1(l3, 512, b.z, b.w) + sample1(l4, 256, b.z, b.w);
    __builtin_nontemporal_store(o, &out[t]);
}

extern "C" void kernel_launch(void* const* d_in, const int* in_sizes, int n_in,
                              void* d_out, int out_size, void* d_ws, size_t ws_size,
                              hipStream_t stream) {
    const vf4* xg = (const vf4*)d_in[0];
    const float* l1 = (const float*)d_in[1];
    const float* l2 = (const float*)d_in[2];
    const float* l3 = (const float*)d_in[3];
    const float* l4 = (const float*)d_in[4];
    vf4* out = (vf4*)d_out;
    int nquads = out_size / 4;                        // 4,194,304
    const size_t R_bytes = (size_t)4096 * 4096 * 8;   // 134,217,728

    if (ws_size >= R_bytes) {
        h4* R = (h4*)d_ws;
        build_R<<<65536, 256, 0, stream>>>(l1, l2, l3, l4, R);
        tex_kernel_fused<<<(nquads + 255) / 256, 256, 0, stream>>>(xg, R, out, nquads);
    } else {
        tex_kernel_direct<<<(nquads + 255) / 256, 256, 0, stream>>>(xg, l1, l2, l3, l4, out, nquads);
    }
}

// Round 4
// 470.864 us; speedup vs baseline: 2.2353x; 1.4311x over previous
//
#include <hip/hip_runtime.h>

typedef float vf4 __attribute__((ext_vector_type(4)));
typedef float vf2 __attribute__((ext_vector_type(2)));
typedef _Float16 h4 __attribute__((ext_vector_type(4)));

// ---------- shared bilinear helpers (zeros padding, align_corners=False) ----------

__device__ __forceinline__ vf2 fetch_pair(const float* __restrict__ tex, int N, int y, int x0) {
    vf2 r = {0.f, 0.f};
    if ((unsigned)y < (unsigned)N) {
        const float* row = tex + (size_t)(unsigned)y * (unsigned)N;
        if ((unsigned)x0 < (unsigned)(N - 1)) {
            __builtin_memcpy(&r, row + x0, sizeof(vf2));   // 4B-aligned 8B load
        } else if (x0 == -1) {
            r.y = row[0];
        } else if (x0 == N - 1) {
            r.x = row[N - 1];
        }
    }
    return r;
}

__device__ __forceinline__ float sample_ix(const float* __restrict__ tex, int N, float ix, float iy) {
    float x0f = floorf(ix);
    float y0f = floorf(iy);
    float wx = ix - x0f;
    float wy = iy - y0f;
    int x0 = (int)x0f;
    int y0 = (int)y0f;
    vf2 t = fetch_pair(tex, N, y0, x0);
    vf2 b = fetch_pair(tex, N, y0 + 1, x0);
    float top = fmaf(wx, t.y - t.x, t.x);
    float bot = fmaf(wx, b.y - b.x, b.x);
    return fmaf(wy, bot - top, top);
}

// Value of the 4-level sum F at fused-grid knot (jx, jy) in units of 1/4096.
__device__ __forceinline__ float knotV(const float* __restrict__ l1, const float* __restrict__ l2,
                                       const float* __restrict__ l3, const float* __restrict__ l4,
                                       float fx, float fy) {
    float s;
    s  = sample_ix(l1, 2048, fmaf(fx, 0.5f,    -0.5f), fmaf(fy, 0.5f,    -0.5f));
    s += sample_ix(l2, 1024, fmaf(fx, 0.25f,   -0.5f), fmaf(fy, 0.25f,   -0.5f));
    s += sample_ix(l3,  512, fmaf(fx, 0.125f,  -0.5f), fmaf(fy, 0.125f,  -0.5f));
    s += sample_ix(l4,  256, fmaf(fx, 0.0625f, -0.5f), fmaf(fy, 0.0625f, -0.5f));
    return s;
}

// ---------- pass 1 (tiled): build fused cell table R[4096][4096] (fp16x4 = 8B/cell) ----------
// Block computes a 65x65 knot patch once into LDS, then packs 64x64 cells.
// R[jy][jx] = (V[jy][jx], V[jy][jx+1], V[jy+1][jx], V[jy+1][jx+1])
__global__ void __launch_bounds__(256) build_R_tiled(
    const float* __restrict__ l1, const float* __restrict__ l2,
    const float* __restrict__ l3, const float* __restrict__ l4,
    h4* __restrict__ R) {
    __shared__ float Vs[65][66];
    const int tx = (blockIdx.x & 63) << 6;
    const int ty = (blockIdx.x >> 6) << 6;
    for (int k = threadIdx.x; k < 65 * 65; k += 256) {
        int ky = k / 65;
        int kx = k - ky * 65;
        Vs[ky][kx] = knotV(l1, l2, l3, l4, (float)(tx + kx), (float)(ty + ky));
    }
    __syncthreads();
    #pragma unroll
    for (int i = 0; i < 16; ++i) {
        int c = (i << 8) + threadIdx.x;     // 0..4095
        int cy = c >> 6;
        int cx = c & 63;
        h4 q = { (_Float16)Vs[cy][cx],     (_Float16)Vs[cy][cx + 1],
                 (_Float16)Vs[cy + 1][cx], (_Float16)Vs[cy + 1][cx + 1] };
        R[(size_t)(ty + cy) * 4096 + (tx + cx)] = q;
    }
}

// ---------- pass 2: one 8B gather + bilinear per pixel ----------
__device__ __forceinline__ float sample_R(const h4* __restrict__ R, float gx, float gy) {
    float u = gx * 4096.0f;
    float v = gy * 4096.0f;
    int jx = min((int)u, 4095);
    int jy = min((int)v, 4095);
    float wx = u - (float)jx;
    float wy = v - (float)jy;
    h4 q = R[((size_t)jy << 12) | (unsigned)jx]; // single aligned 8B gather
    float v00 = (float)q.x, v01 = (float)q.y, v10 = (float)q.z, v11 = (float)q.w;
    float top = fmaf(wx, v01 - v00, v00);
    float bot = fmaf(wx, v11 - v10, v10);
    return fmaf(wy, bot - top, top);
}

__global__ void __launch_bounds__(256) tex_kernel_fused(
    const vf4* __restrict__ xg, const h4* __restrict__ R,
    vf4* __restrict__ out, int nquads) {
    int t = blockIdx.x * blockDim.x + threadIdx.x;
    if (t >= nquads) return;
    vf4 a = __builtin_nontemporal_load(&xg[2 * t]);
    vf4 b = __builtin_nontemporal_load(&xg[2 * t + 1]);
    vf4 o;
    o.x = sample_R(R, a.x, a.y);
    o.y = sample_R(R, a.z, a.w);
    o.z = sample_R(R, b.x, b.y);
    o.w = sample_R(R, b.z, b.w);
    __builtin_nontemporal_store(o, &out[t]);
}

// ---------- fallback: direct 4-level sampling (round-2 kernel, known-good) ----------
__device__ __forceinline__ float sample1(const float* __restrict__ tex, int N, float gx, float gy) {
    return sample_ix(tex, N, fmaf(gx, (float)N, -0.5f), fmaf(gy, (float)N, -0.5f));
}

__global__ void __launch_bounds__(256) tex_kernel_direct(
    const vf4* __restrict__ xg,
    const float* __restrict__ l1, const float* __restrict__ l2,
    const float* __restrict__ l3, const float* __restrict__ l4,
    vf4* __restrict__ out, int nquads) {
    int t = blockIdx.x * blockDim.x + threadIdx.x;
    if (t >= nquads) return;
    vf4 a = __builtin_nontemporal_load(&xg[2 * t]);
    vf4 b = __builtin_nontemporal_load(&xg[2 * t + 1]);
    vf4 o;
    o.x = sample1(l1, 2048, a.x, a.y) + sample1(l2, 1024, a.x, a.y) + sample1(l3, 512, a.x, a.y) + sample1(l4, 256, a.x, a.y);
    o.y = sample1(l1, 2048, a.z, a.w) + sample1(l2, 1024, a.z, a.w) + sample1(l3, 512, a.z, a.w) + sample1(l4, 256, a.z, a.w);
    o.z = sample1(l1, 2048, b.x, b.y) + sample1(l2, 1024, b.x, b.y) + sample1(l3, 512, b.x, b.y) + sample1(l4, 256, b.x, b.y);
    o.w = sample1(l1, 2048, b.z, b.w) + sample1(l2, 1024, b.z, b.w) + sample1(l3, 512, b.z, b.w) + sample1(l4, 256, b.z, b.w);
    __builtin_nontemporal_store(o, &out[t]);
}

extern "C" void kernel_launch(void* const* d_in, const int* in_sizes, int n_in,
                              void* d_out, int out_size, void* d_ws, size_t ws_size,
                              hipStream_t stream) {
    const vf4* xg = (const vf4*)d_in[0];
    const float* l1 = (const float*)d_in[1];
    const float* l2 = (const float*)d_in[2];
    const float* l3 = (const float*)d_in[3];
    const float* l4 = (const float*)d_in[4];
    vf4* out = (vf4*)d_out;
    int nquads = out_size / 4;                        // 4,194,304
    const size_t R_bytes = (size_t)4096 * 4096 * 8;   // 134,217,728

    if (ws_size >= R_bytes) {
        h4* R = (h4*)d_ws;
        build_R_tiled<<<4096, 256, 0, stream>>>(l1, l2, l3, l4, R);
        tex_kernel_fused<<<(nquads + 255) / 256, 256, 0, stream>>>(xg, R, out, nquads);
    } else {
        tex_kernel_direct<<<(nquads + 255) / 256, 256, 0, stream>>>(xg, l1, l2, l3, l4, out, nquads);
    }
}

// Round 5
// 400.475 us; speedup vs baseline: 2.6281x; 1.1758x over previous
//
#include <hip/hip_runtime.h>

typedef float vf4 __attribute__((ext_vector_type(4)));
typedef float vf2 __attribute__((ext_vector_type(2)));
typedef _Float16 h4 __attribute__((ext_vector_type(4)));

// ---------- shared bilinear helpers (zeros padding, align_corners=False) ----------

__device__ __forceinline__ vf2 fetch_pair(const float* __restrict__ tex, int N, int y, int x0) {
    vf2 r = {0.f, 0.f};
    if ((unsigned)y < (unsigned)N) {
        const float* row = tex + (size_t)(unsigned)y * (unsigned)N;
        if ((unsigned)x0 < (unsigned)(N - 1)) {
            __builtin_memcpy(&r, row + x0, sizeof(vf2));   // 4B-aligned 8B load
        } else if (x0 == -1) {
            r.y = row[0];
        } else if (x0 == N - 1) {
            r.x = row[N - 1];
        }
    }
    return r;
}

__device__ __forceinline__ float sample_ix(const float* __restrict__ tex, int N, float ix, float iy) {
    float x0f = floorf(ix);
    float y0f = floorf(iy);
    float wx = ix - x0f;
    float wy = iy - y0f;
    int x0 = (int)x0f;
    int y0 = (int)y0f;
    vf2 t = fetch_pair(tex, N, y0, x0);
    vf2 b = fetch_pair(tex, N, y0 + 1, x0);
    float top = fmaf(wx, t.y - t.x, t.x);
    float bot = fmaf(wx, b.y - b.x, b.x);
    return fmaf(wy, bot - top, top);
}

// ---------- pass 1 (separable, tiled): build fused cell table R[4096][4096] ----------
// Per 64x64-cell tile: phase A x-interpolates the 68 needed texture rows (34+18+10+6
// across the 4 levels) at the 65 knot columns into LDS H. Phase B1 forms the 65x65
// knot values with 4 fused y-lerps each. Phase B2 packs cells:
// R[jy][jx] = (V[jy][jx], V[jy][jx+1], V[jy+1][jx], V[jy+1][jx+1])  as fp16x4.
__global__ void __launch_bounds__(256) build_R_sep(
    const float* __restrict__ l1, const float* __restrict__ l2,
    const float* __restrict__ l3, const float* __restrict__ l4,
    h4* __restrict__ R) {
    __shared__ float H[68][66];
    __shared__ float Vs[65][66];
    const int tx = (blockIdx.x & 63) << 6;
    const int ty = (blockIdx.x >> 6) << 6;

    // Phase A: x-interp texture rows.  slot layout: l1:[0,34) l2:[34,52) l3:[52,62) l4:[62,68)
    for (int w = threadIdx.x; w < 68 * 65; w += 256) {
        int slot = w / 65;              // constant div -> magic mul
        int kx = w - slot * 65;
        const float* tex;
        int N, bs, ry0;
        float cc;
        if (slot < 34)      { tex = l1; N = 2048; cc = 0.5f;    bs = 0;  ry0 = (ty >> 1) - 1; }
        else if (slot < 52) { tex = l2; N = 1024; cc = 0.25f;   bs = 34; ry0 = (ty >> 2) - 1; }
        else if (slot < 62) { tex = l3; N = 512;  cc = 0.125f;  bs = 52; ry0 = (ty >> 3) - 1; }
        else                { tex = l4; N = 256;  cc = 0.0625f; bs = 62; ry0 = (ty >> 4) - 1; }
        int ry = ry0 + (slot - bs);
        float ix = fmaf((float)(tx + kx), cc, -0.5f);
        float x0f = floorf(ix);
        float wx = ix - x0f;
        vf2 p = fetch_pair(tex, N, ry, (int)x0f);   // zeros if ry out of range
        H[slot][kx] = fmaf(wx, p.y - p.x, p.x);
    }
    __syncthreads();

    // Phase B1: knot values = sum of 4 y-lerps from H.
    for (int k = threadIdx.x; k < 65 * 65; k += 256) {
        int ky = k / 65;
        int kx = k - ky * 65;
        float jy = (float)(ty + ky);
        float s = 0.f;
        #pragma unroll
        for (int l = 0; l < 4; ++l) {
            const float cc = (l == 0) ? 0.5f : (l == 1) ? 0.25f : (l == 2) ? 0.125f : 0.0625f;
            const int bs   = (l == 0) ? 0    : (l == 1) ? 34    : (l == 2) ? 52     : 62;
            const int ry0  = (l == 0) ? ((ty >> 1) - 1) : (l == 1) ? ((ty >> 2) - 1)
                           : (l == 2) ? ((ty >> 3) - 1) : ((ty >> 4) - 1);
            float iy = fmaf(jy, cc, -0.5f);
            float y0f = floorf(iy);
            float wy = iy - y0f;
            int slot = bs + ((int)y0f - ry0);
            float a = H[slot][kx];
            float b = H[slot + 1][kx];
            s += fmaf(wy, b - a, a);
        }
        Vs[ky][kx] = s;
    }
    __syncthreads();

    // Phase B2: pack 64x64 cells.
    #pragma unroll
    for (int i = 0; i < 16; ++i) {
        int c = (i << 8) + threadIdx.x;     // 0..4095
        int cy = c >> 6;
        int cx = c & 63;
        h4 q = { (_Float16)Vs[cy][cx],     (_Float16)Vs[cy][cx + 1],
                 (_Float16)Vs[cy + 1][cx], (_Float16)Vs[cy + 1][cx + 1] };
        R[(size_t)(ty + cy) * 4096 + (tx + cx)] = q;
    }
}

// ---------- pass 2: one 8B gather + bilinear per pixel ----------
__device__ __forceinline__ float sample_R(const h4* __restrict__ R, float gx, float gy) {
    float u = gx * 4096.0f;
    float v = gy * 4096.0f;
    int jx = min((int)u, 4095);
    int jy = min((int)v, 4095);
    float wx = u - (float)jx;
    float wy = v - (float)jy;
    h4 q = R[((size_t)jy << 12) | (unsigned)jx]; // single aligned 8B gather
    float v00 = (float)q.x, v01 = (float)q.y, v10 = (float)q.z, v11 = (float)q.w;
    float top = fmaf(wx, v01 - v00, v00);
    float bot = fmaf(wx, v11 - v10, v10);
    return fmaf(wy, bot - top, top);
}

__global__ void __launch_bounds__(256) tex_kernel_fused(
    const vf4* __restrict__ xg, const h4* __restrict__ R,
    vf4* __restrict__ out, int nquads) {
    int t = blockIdx.x * blockDim.x + threadIdx.x;
    if (t >= nquads) return;
    vf4 a = __builtin_nontemporal_load(&xg[2 * t]);
    vf4 b = __builtin_nontemporal_load(&xg[2 * t + 1]);
    vf4 o;
    o.x = sample_R(R, a.x, a.y);
    o.y = sample_R(R, a.z, a.w);
    o.z = sample_R(R, b.x, b.y);
    o.w = sample_R(R, b.z, b.w);
    __builtin_nontemporal_store(o, &out[t]);
}

// ---------- fallback: direct 4-level sampling (round-2 kernel, known-good) ----------
__device__ __forceinline__ float sample1(const float* __restrict__ tex, int N, float gx, float gy) {
    return sample_ix(tex, N, fmaf(gx, (float)N, -0.5f), fmaf(gy, (float)N, -0.5f));
}

__global__ void __launch_bounds__(256) tex_kernel_direct(
    const vf4* __restrict__ xg,
    const float* __restrict__ l1, const float* __restrict__ l2,
    const float* __restrict__ l3, const float* __restrict__ l4,
    vf4* __restrict__ out, int nquads) {
    int t = blockIdx.x * blockDim.x + threadIdx.x;
    if (t >= nquads) return;
    vf4 a = __builtin_nontemporal_load(&xg[2 * t]);
    vf4 b = __builtin_nontemporal_load(&xg[2 * t + 1]);
    vf4 o;
    o.x = sample1(l1, 2048, a.x, a.y) + sample1(l2, 1024, a.x, a.y) + sample1(l3, 512, a.x, a.y) + sample1(l4, 256, a.x, a.y);
    o.y = sample1(l1, 2048, a.z, a.w) + sample1(l2, 1024, a.z, a.w) + sample1(l3, 512, a.z, a.w) + sample1(l4, 256, a.z, a.w);
    o.z = sample1(l1, 2048, b.x, b.y) + sample1(l2, 1024, b.x, b.y) + sample1(l3, 512, b.x, b.y) + sample1(l4, 256, b.x, b.y);
    o.w = sample1(l1, 2048, b.z, b.w) + sample1(l2, 1024, b.z, b.w) + sample1(l3, 512, b.z, b.w) + sample1(l4, 256, b.z, b.w);
    __builtin_nontemporal_store(o, &out[t]);
}

extern "C" void kernel_launch(void* const* d_in, const int* in_sizes, int n_in,
                              void* d_out, int out_size, void* d_ws, size_t ws_size,
                              hipStream_t stream) {
    const vf4* xg = (const vf4*)d_in[0];
    const float* l1 = (const float*)d_in[1];
    const float* l2 = (const float*)d_in[2];
    const float* l3 = (const float*)d_in[3];
    const float* l4 = (const float*)d_in[4];
    vf4* out = (vf4*)d_out;
    int nquads = out_size / 4;                        // 4,194,304
    const size_t R_bytes = (size_t)4096 * 4096 * 8;   // 134,217,728

    if (ws_size >= R_bytes) {
        h4* R = (h4*)d_ws;
        build_R_sep<<<4096, 256, 0, stream>>>(l1, l2, l3, l4, R);
        tex_kernel_fused<<<(nquads + 255) / 256, 256, 0, stream>>>(xg, R, out, nquads);
    } else {
        tex_kernel_direct<<<(nquads + 255) / 256, 256, 0, stream>>>(xg, l1, l2, l3, l4, out, nquads);
    }
}